// Round 11
// baseline (739.442 us; speedup 1.0000x reference)
//
#include <hip/hip_runtime.h>
#include <hip/hip_bf16.h>

using bhalf = __hip_bfloat16;
typedef __bf16 bf16x8 __attribute__((ext_vector_type(8)));
typedef __bf16 bf16x2 __attribute__((ext_vector_type(2)));
typedef float f32x4 __attribute__((ext_vector_type(4)));

#define B_DIM 2
#define T_DIM 2048
#define D_DIM 1024
#define H_DIM 16
#define DH 64

struct bh8 { bhalf v[8]; };
struct bh4 { bhalf v[4]; };

__device__ __forceinline__ bf16x8 load_bf16x8(const bhalf* p) {
    return __builtin_bit_cast(bf16x8, *(const uint4*)p);
}
__device__ __forceinline__ bf16x8 zero_bf16x8() {
    uint4 z; z.x = 0; z.y = 0; z.z = 0; z.w = 0;
    return __builtin_bit_cast(bf16x8, z);
}
__device__ __forceinline__ void stage8_cvt(bhalf* dst, const float* src) {
    float4 a = *(const float4*)src;
    float4 b = *(const float4*)(src + 4);
    bh8 t;
    t.v[0] = __float2bfloat16(a.x); t.v[1] = __float2bfloat16(a.y);
    t.v[2] = __float2bfloat16(a.z); t.v[3] = __float2bfloat16(a.w);
    t.v[4] = __float2bfloat16(b.x); t.v[5] = __float2bfloat16(b.y);
    t.v[6] = __float2bfloat16(b.z); t.v[7] = __float2bfloat16(b.w);
    *(uint4*)dst = __builtin_bit_cast(uint4, t);
}

// async 16B global -> LDS (wave-uniform LDS base + lane*16)
#define GLD16(gp, lp) __builtin_amdgcn_global_load_lds( \
    (const __attribute__((address_space(1))) void*)(gp), \
    (__attribute__((address_space(3))) void*)(lp), 16, 0, 0)

#define SX  4194304
#define SW  3145728
#define CVT_BLOCKS 3584     // (SX+SW)/2048
#define LINES_BLOCKS 274    // ceil(4096/15)

// prep: blocks [0,3584) convert x,wqkv -> bf16; blocks [3584,3858) compute the
// 256-col lines projection (15 tokens + 1 halo row) and build read8/jw8.
__global__ __launch_bounds__(256) void prep(
    const float* __restrict__ x, const float* __restrict__ wqkv,
    const float* __restrict__ w1w, const float* __restrict__ w2w,
    const float* __restrict__ w1r, const float* __restrict__ w2r,
    const float* __restrict__ bias_scale, const float* __restrict__ decay_logits,
    bhalf* __restrict__ xbf, bhalf* __restrict__ wcat,
    bhalf* __restrict__ read8, bhalf* __restrict__ jw8)
{
    __shared__ bhalf Bs[256 * 72];   // 36864 B (reused as f32 C-tile 16x260)
    __shared__ bhalf As[16 * 72];
    const int tid = threadIdx.x;
    const int bx = blockIdx.x;
    if (bx < CVT_BLOCKS) {
        int i = bx * 2048 + tid * 8;
        if (i < SX) stage8_cvt(xbf + i, x + i);
        else        stage8_cvt(wcat + (i - SX), wqkv + (i - SX));
        return;
    }
    const int lb = bx - CVT_BLOCKS;
    const int T0 = lb * 15;
    const int wave = tid >> 6, lane = tid & 63;
    const int ln = lane & 15, lg = lane >> 4;

    const float* wsel = (tid < 64) ? w1w : (tid < 128) ? w2w : (tid < 192) ? w1r : w2r;
    const float* brow = wsel + (size_t)(tid & 63) * D_DIM;

    f32x4 acc[4] = {};
    for (int kt = 0; kt < D_DIM; kt += 64) {
        __syncthreads();
        {   // A: 16 rows (tokens T0-1 .. T0+14, clamped)
            int r = tid >> 4;
            int c4 = (tid & 15) * 4;
            int tokrow = T0 - 1 + r;
            tokrow = min(max(tokrow, 0), B_DIM * T_DIM - 1);
            float4 a = *(const float4*)&x[(size_t)tokrow * D_DIM + kt + c4];
            bh4 pk;
            pk.v[0] = __float2bfloat16(a.x); pk.v[1] = __float2bfloat16(a.y);
            pk.v[2] = __float2bfloat16(a.z); pk.v[3] = __float2bfloat16(a.w);
            *(uint2*)&As[r * 72 + c4] = __builtin_bit_cast(uint2, pk);
        }
        // B: 256 weight rows, one per thread
#pragma unroll
        for (int c8 = 0; c8 < 64; c8 += 8)
            stage8_cvt(&Bs[tid * 72 + c8], brow + kt + c8);
        __syncthreads();
#pragma unroll
        for (int ks = 0; ks < 2; ++ks) {
            bf16x8 af = load_bf16x8(&As[ln * 72 + ks * 32 + lg * 8]);
#pragma unroll
            for (int nt = 0; nt < 4; ++nt) {
                bf16x8 bfr = load_bf16x8(&Bs[(wave * 64 + nt * 16 + ln) * 72 + ks * 32 + lg * 8]);
                acc[nt] = __builtin_amdgcn_mfma_f32_16x16x32_bf16(af, bfr, acc[nt], 0, 0, 0);
            }
        }
    }
    float* smC = (float*)Bs;   // [16][260]
    __syncthreads();
#pragma unroll
    for (int nt = 0; nt < 4; ++nt)
#pragma unroll
        for (int r = 0; r < 4; ++r)
            smC[(lg * 4 + r) * 260 + wave * 64 + nt * 16 + ln] = acc[nt][r];
    __syncthreads();

    int t_local = tid >> 4;   // 0..15
    int h = tid & 15;
    int token = T0 + t_local;
    if (t_local < 15 && token < B_DIM * T_DIM) {
        int t = token & (T_DIM - 1);
        int b = token >> 11;
        const float* prow  = &smC[(t_local + 1) * 260];
        const float* pprev = &smC[t_local * 260];
        float p1[4], p2[4], r1[4], r2[4];
#pragma unroll
        for (int i = 0; i < 4; ++i) {
            p1[i] = (t > 0) ? pprev[h * 4 + i] : 0.f;
            p2[i] = prow[64 + h * 4 + i];
            r1[i] = prow[128 + h * 4 + i];
            r2[i] = prow[192 + h * 4 + i];
        }
        float Lw[6], Lr[6];
        Lw[0] = p1[0] * p2[1] - p1[1] * p2[0];
        Lw[1] = p1[0] * p2[2] - p1[2] * p2[0];
        Lw[2] = p1[0] * p2[3] - p1[3] * p2[0];
        Lw[3] = p1[1] * p2[2] - p1[2] * p2[1];
        Lw[4] = p1[1] * p2[3] - p1[3] * p2[1];
        Lw[5] = p1[2] * p2[3] - p1[3] * p2[2];
        float n2w = 0.f;
#pragma unroll
        for (int j = 0; j < 6; ++j) n2w += Lw[j] * Lw[j];
        float invw = 1.f / fmaxf(sqrtf(n2w), 1e-12f);
#pragma unroll
        for (int j = 0; j < 6; ++j) Lw[j] *= invw;
        Lr[0] = r1[0] * r2[1] - r1[1] * r2[0];
        Lr[1] = r1[0] * r2[2] - r1[2] * r2[0];
        Lr[2] = r1[0] * r2[3] - r1[3] * r2[0];
        Lr[3] = r1[1] * r2[2] - r1[2] * r2[1];
        Lr[4] = r1[1] * r2[3] - r1[3] * r2[1];
        Lr[5] = r1[2] * r2[3] - r1[3] * r2[2];
        float n2r = 0.f;
#pragma unroll
        for (int j = 0; j < 6; ++j) n2r += Lr[j] * Lr[j];
        float invr = 1.f / fmaxf(sqrtf(n2r), 1e-12f);
#pragma unroll
        for (int j = 0; j < 6; ++j) Lr[j] *= invr;

        float decay = 1.f / (1.f + __expf(-decay_logits[h]));
        float l2d = log2f(decay);
        float bs = bias_scale[h] * exp2f(-(float)t * l2d);
        size_t base = (((size_t)(b * H_DIM + h)) * T_DIM + t) * 8;
        bh8 ro, jo;
        ro.v[0] = __float2bfloat16(Lr[0]); ro.v[1] = __float2bfloat16(Lr[1]);
        ro.v[2] = __float2bfloat16(Lr[2]); ro.v[3] = __float2bfloat16(Lr[3]);
        ro.v[4] = __float2bfloat16(Lr[4]); ro.v[5] = __float2bfloat16(Lr[5]);
        ro.v[6] = __float2bfloat16(0.f);   ro.v[7] = __float2bfloat16(0.f);
        *(uint4*)&read8[base] = __builtin_bit_cast(uint4, ro);
        jo.v[0] = __float2bfloat16(Lw[5] * bs);  jo.v[1] = __float2bfloat16(-Lw[4] * bs);
        jo.v[2] = __float2bfloat16(Lw[3] * bs);  jo.v[3] = __float2bfloat16(Lw[2] * bs);
        jo.v[4] = __float2bfloat16(-Lw[1] * bs); jo.v[5] = __float2bfloat16(Lw[0] * bs);
        jo.v[6] = __float2bfloat16(0.f);         jo.v[7] = __float2bfloat16(0.f);
        *(uint4*)&jw8[base] = __builtin_bit_cast(uint4, jo);
    }
}

// ---------------- 128x128 tile GEMM: C = A(128xK) * B(128xK)^T ----------------
__device__ __forceinline__ void gemm128_mainloop(
    const bhalf* __restrict__ A, const bhalf* __restrict__ B, int K,
    bhalf* As, bhalf* Bs, f32x4 acc[4][4])
{
    const int tid = threadIdx.x;
    const int wave = tid >> 6, lane = tid & 63;
    const int ln = lane & 15, lg = lane >> 4;
    const int wr = (wave >> 1) * 64, wc = (wave & 1) * 64;
    const int lrow = lane >> 3;
    const int lcol = (lane & 7) * 8;

    for (int kt = 0; kt < K; kt += 64) {
        __syncthreads();
#pragma unroll
        for (int i = 0; i < 4; ++i) {
            int idx = __builtin_amdgcn_readfirstlane(wave * 4 + i);
            GLD16(A + (size_t)(idx * 8 + lrow) * K + kt + lcol, As + idx * 512);
            GLD16(B + (size_t)(idx * 8 + lrow) * K + kt + lcol, Bs + idx * 512);
        }
        __syncthreads();
#pragma unroll
        for (int ks = 0; ks < 2; ++ks) {
            bf16x8 af[4], bfr[4];
#pragma unroll
            for (int mt = 0; mt < 4; ++mt)
                af[mt] = load_bf16x8(As + (wr + mt * 16 + ln) * 64 + ks * 32 + lg * 8);
#pragma unroll
            for (int nt = 0; nt < 4; ++nt)
                bfr[nt] = load_bf16x8(Bs + (wc + nt * 16 + ln) * 64 + ks * 32 + lg * 8);
#pragma unroll
            for (int mt = 0; mt < 4; ++mt)
#pragma unroll
                for (int nt = 0; nt < 4; ++nt)
                    acc[mt][nt] = __builtin_amdgcn_mfma_f32_16x16x32_bf16(af[mt], bfr[nt], acc[mt][nt], 0, 0, 0);
        }
    }
}

__global__ __launch_bounds__(256) void qkv_gemm128(
    const bhalf* __restrict__ x, const bhalf* __restrict__ wcat, const float* __restrict__ bqkv,
    bhalf* __restrict__ qo, bhalf* __restrict__ ko, bhalf* __restrict__ vt)
{
    __shared__ bhalf As[128 * 64];
    __shared__ bhalf Bs[128 * 64];
    f32x4 acc[4][4] = {};
    gemm128_mainloop(x + (size_t)blockIdx.x * 128 * D_DIM,
                     wcat + (size_t)blockIdx.y * 128 * D_DIM, D_DIM, As, Bs, acc);
    const int wave = threadIdx.x >> 6, lane = threadIdx.x & 63;
    const int ln = lane & 15, lg = lane >> 4;
    const int wr = (wave >> 1) * 64, wc = (wave & 1) * 64;
    const int trip = (blockIdx.y * 128) >> 10;

    if (trip == 2) {
#pragma unroll
        for (int nt = 0; nt < 4; ++nt) {
            int n = blockIdx.y * 128 + wc + nt * 16 + ln;
            float bias = bqkv[n];
            int h = (n >> 6) & 15, d = n & 63;
#pragma unroll
            for (int mt = 0; mt < 4; ++mt) {
                int tok0 = blockIdx.x * 128 + wr + mt * 16 + lg * 4;
                int b = tok0 >> 11, t0 = tok0 & (T_DIM - 1);
                bh4 pk;
#pragma unroll
                for (int r = 0; r < 4; ++r)
                    pk.v[r] = __float2bfloat16(acc[mt][nt][r] + bias);
                *(uint2*)&vt[(((size_t)(b * H_DIM + h)) * DH + d) * T_DIM + t0] =
                    __builtin_bit_cast(uint2, pk);
            }
        }
    } else {
#pragma unroll
        for (int nt = 0; nt < 4; ++nt) {
            int n = blockIdx.y * 128 + wc + nt * 16 + ln;
            int h = (n >> 6) & 15, d = n & 63;
            float bias = bqkv[n];
#pragma unroll
            for (int mt = 0; mt < 4; ++mt)
#pragma unroll
                for (int r = 0; r < 4; ++r) {
                    int tok = blockIdx.x * 128 + wr + mt * 16 + lg * 4 + r;
                    int b = tok >> 11, t = tok & (T_DIM - 1);
                    float y = acc[mt][nt][r] + bias;
                    if (trip == 0) {
                        qo[(((size_t)(b * H_DIM + h)) * T_DIM + t) * DH + d] = __float2bfloat16(y * 0.125f);
                    } else {
                        ko[(((size_t)(b * H_DIM + h)) * T_DIM + t) * DH + d] = __float2bfloat16(y);
                    }
                }
        }
    }
}

// 64x64 bf16 GEMM, A via global_load_lds, B staged from f32 (wout)
__global__ __launch_bounds__(256) void out_gemm64(
    const bhalf* __restrict__ a, const float* __restrict__ w, const float* __restrict__ bo,
    float* __restrict__ out)
{
    __shared__ bhalf As[64 * 64];
    __shared__ bhalf Bs[64 * 72];
    const int tid = threadIdx.x;
    const int wave = tid >> 6, lane = tid & 63;
    const int ln = lane & 15, lg = lane >> 4;
    const int lrow = lane >> 3;
    const int lcol = (lane & 7) * 8;
    const bhalf* A = a + (size_t)blockIdx.x * 64 * D_DIM;
    const float* W = w + (size_t)blockIdx.y * 64 * D_DIM;
    f32x4 acc[4] = {};

    const int br = tid >> 2;          // 0..63
    const int bc = (tid & 3) * 16;    // 0,16,32,48

    for (int kt = 0; kt < D_DIM; kt += 64) {
        __syncthreads();
#pragma unroll
        for (int i = 0; i < 2; ++i) {
            int idx = __builtin_amdgcn_readfirstlane(wave * 2 + i);
            GLD16(A + (size_t)(idx * 8 + lrow) * D_DIM + kt + lcol, As + idx * 512);
        }
        stage8_cvt(&Bs[br * 72 + bc], W + (size_t)br * D_DIM + kt + bc);
        stage8_cvt(&Bs[br * 72 + bc + 8], W + (size_t)br * D_DIM + kt + bc + 8);
        __syncthreads();
#pragma unroll
        for (int ks = 0; ks < 2; ++ks) {
            bf16x8 af = load_bf16x8(As + (wave * 16 + ln) * 64 + ks * 32 + lg * 8);
#pragma unroll
            for (int nt = 0; nt < 4; ++nt) {
                bf16x8 bfr = load_bf16x8(&Bs[(nt * 16 + ln) * 72 + ks * 32 + lg * 8]);
                acc[nt] = __builtin_amdgcn_mfma_f32_16x16x32_bf16(af, bfr, acc[nt], 0, 0, 0);
            }
        }
    }
#pragma unroll
    for (int nt = 0; nt < 4; ++nt) {
        int n = blockIdx.y * 64 + nt * 16 + ln;
        float bias = bo[n];
#pragma unroll
        for (int r = 0; r < 4; ++r) {
            int tok = blockIdx.x * 64 + wave * 16 + lg * 4 + r;
            out[(size_t)tok * D_DIM + n] = acc[nt][r] + bias;
        }
    }
}

// softmax tile step
template<bool DIAG>
__device__ __forceinline__ void tile_step(
    const f32x4& z0, const f32x4& z1, const f32x4& i0, const f32x4& i1,
    int rq, int kb, const float* aq, int lg, int ln, bhalf* pl, float* lp)
{
    const float LOG2E = 1.44269504f;
#pragma unroll
    for (int r = 0; r < 4; ++r) {
        float p0, p1;
        if (DIAG) {
            int diff0 = rq + lg * 4 + r - (kb + 2 * ln);
            float s0 = z0[r] + ((diff0 > 0) ? i0[r] * aq[r] : 0.f);
            p0 = (diff0 < 0) ? 0.f : exp2f(s0 * LOG2E);
            int diff1 = diff0 - 1;
            float s1 = z1[r] + ((diff1 > 0) ? i1[r] * aq[r] : 0.f);
            p1 = (diff1 < 0) ? 0.f : exp2f(s1 * LOG2E);
        } else {
            p0 = exp2f(fmaf(i0[r], aq[r], z0[r]) * LOG2E);
            p1 = exp2f(fmaf(i1[r], aq[r], z1[r]) * LOG2E);
        }
        bf16x2 h2;
        h2.x = (__bf16)p0;
        h2.y = (__bf16)p1;
        *(unsigned int*)&pl[(lg * 4 + r) * 40 + 2 * ln] = __builtin_bit_cast(unsigned int, h2);
        lp[r] += p0 + p1;
    }
}

// Attention, antithetic-paired, paired-k, fast/diag paths. launch_bounds(256,6):
// force VGPR<=85 -> 6 waves/SIMD (occupancy experiment; was 96 VGPR / 5 waves).
__global__ __launch_bounds__(256, 6) void attn_kernel(
    const bhalf* __restrict__ q, const bhalf* __restrict__ k, const bhalf* __restrict__ vt,
    const bhalf* __restrict__ read8, const bhalf* __restrict__ jw8,
    const float* __restrict__ decay_logits, bhalf* __restrict__ attn_out)
{
    __shared__ float sm[4352];   // 17408 B
    const int wave = threadIdx.x >> 6, lane = threadIdx.x & 63;
    const int ln = lane & 15, lg = lane >> 4;
    const int h = blockIdx.y, b = blockIdx.z;
    const int qa = blockIdx.x;
    const int qb = 127 - qa;
    const int rqa = qa * 16, rqb = qb * 16;
    const size_t hb = (size_t)(b * H_DIM + h);
    const bhalf* qh = q + hb * T_DIM * DH;
    const bhalf* kh = k + hb * T_DIM * DH;
    const bhalf* vh = vt + hb * DH * T_DIM;
    const bhalf* r8 = read8 + hb * T_DIM * 8;
    const bhalf* j8 = jw8 + hb * T_DIM * 8;

    bhalf* plA = (bhalf*)sm + wave * 640;
    bhalf* plB = (bhalf*)sm + 2560 + wave * 640;

    bf16x8 zf = zero_bf16x8();
    bf16x8 qA0 = load_bf16x8(qh + (rqa + ln) * DH + lg * 8);
    bf16x8 qA1 = load_bf16x8(qh + (rqa + ln) * DH + 32 + lg * 8);
    bf16x8 qB0 = load_bf16x8(qh + (rqb + ln) * DH + lg * 8);
    bf16x8 qB1 = load_bf16x8(qh + (rqb + ln) * DH + 32 + lg * 8);
    bf16x8 rfA = (lane < 16) ? load_bf16x8(r8 + (size_t)(rqa + ln) * 8) : zf;
    bf16x8 rfB = (lane < 16) ? load_bf16x8(r8 + (size_t)(rqb + ln) * 8) : zf;

    float decay = 1.f / (1.f + __expf(-decay_logits[h]));
    float l2d = log2f(decay);
    float aqA[4], aqB[4];
#pragma unroll
    for (int r = 0; r < 4; ++r) {
        aqA[r] = exp2f((float)(rqa + lg * 4 + r) * l2d);
        aqB[r] = exp2f((float)(rqb + lg * 4 + r) * l2d);
    }

    f32x4 oA[4] = {}, oB[4] = {};
    float lpA[4] = {0.f, 0.f, 0.f, 0.f}, lpB[4] = {0.f, 0.f, 0.f, 0.f};

    const int nca = qa / 2 + 1, ncb = qb / 2 + 1;
    for (int c = wave; c < ncb; c += 4) {
        const int kb = c * 32;
        bf16x8 k00 = load_bf16x8(kh + (kb + 2 * ln) * DH + lg * 8);
        bf16x8 k01 = load_bf16x8(kh + (kb + 2 * ln) * DH + 32 + lg * 8);
        bf16x8 k10 = load_bf16x8(kh + (kb + 2 * ln + 1) * DH + lg * 8);
        bf16x8 k11 = load_bf16x8(kh + (kb + 2 * ln + 1) * DH + 32 + lg * 8);
        bf16x8 j0 = (lane < 16) ? load_bf16x8(j8 + (size_t)(kb + 2 * ln) * 8) : zf;
        bf16x8 j1 = (lane < 16) ? load_bf16x8(j8 + (size_t)(kb + 2 * ln + 1) * 8) : zf;
        bf16x8 vf0 = load_bf16x8(vh + (size_t)(ln) * T_DIM + kb + lg * 8);
        bf16x8 vf1 = load_bf16x8(vh + (size_t)(16 + ln) * T_DIM + kb + lg * 8);
        bf16x8 vf2 = load_bf16x8(vh + (size_t)(32 + ln) * T_DIM + kb + lg * 8);
        bf16x8 vf3 = load_bf16x8(vh + (size_t)(48 + ln) * T_DIM + kb + lg * 8);
        const bool doA = (c < nca);

        {
            f32x4 z0 = {}, z1 = {}, i0 = {}, i1 = {};
            z0 = __builtin_amdgcn_mfma_f32_16x16x32_bf16(qB0, k00, z0, 0, 0, 0);
            z0 = __builtin_amdgcn_mfma_f32_16x16x32_bf16(qB1, k01, z0, 0, 0, 0);
            i0 = __builtin_amdgcn_mfma_f32_16x16x32_bf16(rfB, j0, i0, 0, 0, 0);
            z1 = __builtin_amdgcn_mfma_f32_16x16x32_bf16(qB0, k10, z1, 0, 0, 0);
            z1 = __builtin_amdgcn_mfma_f32_16x16x32_bf16(qB1, k11, z1, 0, 0, 0);
            i1 = __builtin_amdgcn_mfma_f32_16x16x32_bf16(rfB, j1, i1, 0, 0, 0);
            if (c == ncb - 1) tile_step<true >(z0, z1, i0, i1, rqb, kb, aqB, lg, ln, plB, lpB);
            else              tile_step<false>(z0, z1, i0, i1, rqb, kb, aqB, lg, ln, plB, lpB);
        }
        if (doA) {
            f32x4 z0 = {}, z1 = {}, i0 = {}, i1 = {};
            z0 = __builtin_amdgcn_mfma_f32_16x16x32_bf16(qA0, k00, z0, 0, 0, 0);
            z0 = __builtin_amdgcn_mfma_f32_16x16x32_bf16(qA1, k01, z0, 0, 0, 0);
            i0 = __builtin_amdgcn_mfma_f32_16x16x32_bf16(rfA, j0, i0, 0, 0, 0);
            z1 = __builtin_amdgcn_mfma_f32_16x16x32_bf16(qA0, k10, z1, 0, 0, 0);
            z1 = __builtin_amdgcn_mfma_f32_16x16x32_bf16(qA1, k11, z1, 0, 0, 0);
            i1 = __builtin_amdgcn_mfma_f32_16x16x32_bf16(rfA, j1, i1, 0, 0, 0);
            if (c == nca - 1) tile_step<true >(z0, z1, i0, i1, rqa, kb, aqA, lg, ln, plA, lpA);
            else              tile_step<false>(z0, z1, i0, i1, rqa, kb, aqA, lg, ln, plA, lpA);
        }
        __asm__ volatile("s_waitcnt lgkmcnt(0)" ::: "memory");
        {
            bf16x8 pf = load_bf16x8(plB + ln * 40 + lg * 8);
            oB[0] = __builtin_amdgcn_mfma_f32_16x16x32_bf16(pf, vf0, oB[0], 0, 0, 0);
            oB[1] = __builtin_amdgcn_mfma_f32_16x16x32_bf16(pf, vf1, oB[1], 0, 0, 0);
            oB[2] = __builtin_amdgcn_mfma_f32_16x16x32_bf16(pf, vf2, oB[2], 0, 0, 0);
            oB[3] = __builtin_amdgcn_mfma_f32_16x16x32_bf16(pf, vf3, oB[3], 0, 0, 0);
        }
        if (doA) {
            bf16x8 pf = load_bf16x8(plA + ln * 40 + lg * 8);
            oA[0] = __builtin_amdgcn_mfma_f32_16x16x32_bf16(pf, vf0, oA[0], 0, 0, 0);
            oA[1] = __builtin_amdgcn_mfma_f32_16x16x32_bf16(pf, vf1, oA[1], 0, 0, 0);
            oA[2] = __builtin_amdgcn_mfma_f32_16x16x32_bf16(pf, vf2, oA[2], 0, 0, 0);
            oA[3] = __builtin_amdgcn_mfma_f32_16x16x32_bf16(pf, vf3, oA[3], 0, 0, 0);
        }
    }

#pragma unroll
    for (int r = 0; r < 4; ++r) {
#pragma unroll
        for (int off = 1; off < 16; off <<= 1) {
            lpA[r] += __shfl_xor(lpA[r], off, 16);
            lpB[r] += __shfl_xor(lpB[r], off, 16);
        }
    }

    const int row = threadIdx.x >> 4;
    const int c4 = (threadIdx.x & 15) * 4;

    __syncthreads();
#pragma unroll
    for (int r = 0; r < 4; ++r) {
        if (ln == 0) sm[wave * 1088 + (lg * 4 + r) * 68 + 64] = lpA[r];
#pragma unroll
        for (int nt = 0; nt < 4; ++nt)
            sm[wave * 1088 + (lg * 4 + r) * 68 + nt * 16 + ln] = oA[nt][r];
    }
    __syncthreads();
    {
        float l = 0.f;
#pragma unroll
        for (int w = 0; w < 4; ++w) l += sm[w * 1088 + row * 68 + 64];
        float4 acc = {0.f, 0.f, 0.f, 0.f};
#pragma unroll
        for (int w = 0; w < 4; ++w) {
            float4 t = *(const float4*)&sm[w * 1088 + row * 68 + c4];
            acc.x += t.x; acc.y += t.y; acc.z += t.z; acc.w += t.w;
        }
        float invl = 1.f / l;
        bh4 pk;
        pk.v[0] = __float2bfloat16(acc.x * invl);
        pk.v[1] = __float2bfloat16(acc.y * invl);
        pk.v[2] = __float2bfloat16(acc.z * invl);
        pk.v[3] = __float2bfloat16(acc.w * invl);
        size_t tok = (size_t)b * T_DIM + rqa + row;
        *(uint2*)&attn_out[tok * D_DIM + h * DH + c4] = __builtin_bit_cast(uint2, pk);
    }

    __syncthreads();
#pragma unroll
    for (int r = 0; r < 4; ++r) {
        if (ln == 0) sm[wave * 1088 + (lg * 4 + r) * 68 + 64] = lpB[r];
#pragma unroll
        for (int nt = 0; nt < 4; ++nt)
            sm[wave * 1088 + (lg * 4 + r) * 68 + nt * 16 + ln] = oB[nt][r];
    }
    __syncthreads();
    {
        float l = 0.f;
#pragma unroll
        for (int w = 0; w < 4; ++w) l += sm[w * 1088 + row * 68 + 64];
        float4 acc = {0.f, 0.f, 0.f, 0.f};
#pragma unroll
        for (int w = 0; w < 4; ++w) {
            float4 t = *(const float4*)&sm[w * 1088 + row * 68 + c4];
            acc.x += t.x; acc.y += t.y; acc.z += t.z; acc.w += t.w;
        }
        float invl = 1.f / l;
        bh4 pk;
        pk.v[0] = __float2bfloat16(acc.x * invl);
        pk.v[1] = __float2bfloat16(acc.y * invl);
        pk.v[2] = __float2bfloat16(acc.z * invl);
        pk.v[3] = __float2bfloat16(acc.w * invl);
        size_t tok = (size_t)b * T_DIM + rqb + row;
        *(uint2*)&attn_out[tok * D_DIM + h * DH + c4] = __builtin_bit_cast(uint2, pk);
    }
}

extern "C" void kernel_launch(void* const* d_in, const int* in_sizes, int n_in,
                              void* d_out, int out_size, void* d_ws, size_t ws_size,
                              hipStream_t stream)
{
    const float* x    = (const float*)d_in[0];
    const float* wqkv = (const float*)d_in[1];
    const float* bqkv = (const float*)d_in[2];
    const float* w1w  = (const float*)d_in[3];
    const float* w2w  = (const float*)d_in[4];
    const float* w1r  = (const float*)d_in[5];
    const float* w2r  = (const float*)d_in[6];
    const float* wout = (const float*)d_in[7];
    const float* bout = (const float*)d_in[8];
    const float* dlog = (const float*)d_in[9];
    const float* bsc  = (const float*)d_in[10];
    float* out = (float*)d_out;

    char* ws = (char*)d_ws;
    bhalf* qb    = (bhalf*)(ws);                 // [B,H,T,64] bf16   8388608 B
    bhalf* kbuf  = (bhalf*)(ws + 8388608);       // [B,H,T,64] bf16   8388608 B
    bhalf* vtb   = (bhalf*)(ws + 16777216);      // [B,H,64,T] bf16   8388608 B
    bhalf* r8    = (bhalf*)(ws + 25165824);      // [B,H,T,8]  bf16   1048576 B
    bhalf* j8    = (bhalf*)(ws + 26214400);      // [B,H,T,8]  bf16   1048576 B
    bhalf* ao    = (bhalf*)(ws + 27262976);      // [B*T,1024] bf16   8388608 B

    // d_out doubles as scratch for bf16 x and wqkv (dead before out_gemm writes)
    bhalf* xbf  = (bhalf*)d_out;                      // 8388608 B
    bhalf* wcat = (bhalf*)((char*)d_out + 8388608);   // 6291456 B (3072x1024)

    prep<<<CVT_BLOCKS + LINES_BLOCKS, 256, 0, stream>>>(
        x, wqkv, w1w, w2w, w1r, w2r, bsc, dlog, xbf, wcat, r8, j8);
    qkv_gemm128<<<dim3(32, 24), 256, 0, stream>>>(xbf, wcat, bqkv, qb, kbuf, vtb);
    attn_kernel<<<dim3(64, H_DIM, B_DIM), 256, 0, stream>>>(qb, kbuf, vtb, r8, j8, dlog, ao);
    out_gemm64<<<dim3(64, 16), 256, 0, stream>>>(ao, wout, bout, out);
}

// Round 12
// 285.432 us; speedup vs baseline: 2.5906x; 2.5906x over previous
//
#include <hip/hip_runtime.h>
#include <hip/hip_bf16.h>

using bhalf = __hip_bfloat16;
typedef __bf16 bf16x8 __attribute__((ext_vector_type(8)));
typedef __bf16 bf16x2 __attribute__((ext_vector_type(2)));
typedef float f32x4 __attribute__((ext_vector_type(4)));

#define B_DIM 2
#define T_DIM 2048
#define D_DIM 1024
#define H_DIM 16
#define DH 64

struct bh8 { bhalf v[8]; };
struct bh4 { bhalf v[4]; };

__device__ __forceinline__ bf16x8 load_bf16x8(const bhalf* p) {
    return __builtin_bit_cast(bf16x8, *(const uint4*)p);
}
__device__ __forceinline__ bf16x8 zero_bf16x8() {
    uint4 z; z.x = 0; z.y = 0; z.z = 0; z.w = 0;
    return __builtin_bit_cast(bf16x8, z);
}
__device__ __forceinline__ void stage8_cvt(bhalf* dst, const float* src) {
    float4 a = *(const float4*)src;
    float4 b = *(const float4*)(src + 4);
    bh8 t;
    t.v[0] = __float2bfloat16(a.x); t.v[1] = __float2bfloat16(a.y);
    t.v[2] = __float2bfloat16(a.z); t.v[3] = __float2bfloat16(a.w);
    t.v[4] = __float2bfloat16(b.x); t.v[5] = __float2bfloat16(b.y);
    t.v[6] = __float2bfloat16(b.z); t.v[7] = __float2bfloat16(b.w);
    *(uint4*)dst = __builtin_bit_cast(uint4, t);
}

// async 16B global -> LDS (wave-uniform LDS base + lane*16)
#define GLD16(gp, lp) __builtin_amdgcn_global_load_lds( \
    (const __attribute__((address_space(1))) void*)(gp), \
    (__attribute__((address_space(3))) void*)(lp), 16, 0, 0)

// Segment sizes (elements)
#define SX  4194304
#define SW  3145728
#define SL  65536
#define SO  1048576
__global__ __launch_bounds__(256) void cvt_all(
    const float* __restrict__ x, const float* __restrict__ wqkv,
    const float* __restrict__ w1w, const float* __restrict__ w2w,
    const float* __restrict__ w1r, const float* __restrict__ w2r,
    const float* __restrict__ wout,
    bhalf* __restrict__ xbf, bhalf* __restrict__ wcat, bhalf* __restrict__ woutbf)
{
    int i = (blockIdx.x * 256 + threadIdx.x) * 8;
    if (i < SX) { stage8_cvt(xbf + i, x + i); return; }
    i -= SX;
    if (i < SW) { stage8_cvt(wcat + i, wqkv + i); return; }
    i -= SW;
    if (i < SL) { stage8_cvt(wcat + SW + i, w1w + i); return; }
    i -= SL;
    if (i < SL) { stage8_cvt(wcat + SW + SL + i, w2w + i); return; }
    i -= SL;
    if (i < SL) { stage8_cvt(wcat + SW + 2 * SL + i, w1r + i); return; }
    i -= SL;
    if (i < SL) { stage8_cvt(wcat + SW + 3 * SL + i, w2r + i); return; }
    i -= SL;
    if (i < SO) { stage8_cvt(woutbf + i, wout + i); }
}

// ---------------- 128x128 tile GEMM: C = A(128xK) * B(128xK)^T ----------------
__device__ __forceinline__ void gemm128_mainloop(
    const bhalf* __restrict__ A, const bhalf* __restrict__ B, int K,
    bhalf* As, bhalf* Bs, f32x4 acc[4][4])
{
    const int tid = threadIdx.x;
    const int wave = tid >> 6, lane = tid & 63;
    const int ln = lane & 15, lg = lane >> 4;
    const int wr = (wave >> 1) * 64, wc = (wave & 1) * 64;
    const int lrow = lane >> 3;
    const int lcol = (lane & 7) * 8;

    for (int kt = 0; kt < K; kt += 64) {
        __syncthreads();
#pragma unroll
        for (int i = 0; i < 4; ++i) {
            int idx = __builtin_amdgcn_readfirstlane(wave * 4 + i);
            GLD16(A + (size_t)(idx * 8 + lrow) * K + kt + lcol, As + idx * 512);
            GLD16(B + (size_t)(idx * 8 + lrow) * K + kt + lcol, Bs + idx * 512);
        }
        __syncthreads();
#pragma unroll
        for (int ks = 0; ks < 2; ++ks) {
            bf16x8 af[4], bfr[4];
#pragma unroll
            for (int mt = 0; mt < 4; ++mt)
                af[mt] = load_bf16x8(As + (wr + mt * 16 + ln) * 64 + ks * 32 + lg * 8);
#pragma unroll
            for (int nt = 0; nt < 4; ++nt)
                bfr[nt] = load_bf16x8(Bs + (wc + nt * 16 + ln) * 64 + ks * 32 + lg * 8);
#pragma unroll
            for (int mt = 0; mt < 4; ++mt)
#pragma unroll
                for (int nt = 0; nt < 4; ++nt)
                    acc[mt][nt] = __builtin_amdgcn_mfma_f32_16x16x32_bf16(af[mt], bfr[nt], acc[mt][nt], 0, 0, 0);
        }
    }
}

// fused qkv + lines projection: B = [w_qkv(3072); w1w;w2w;w1r;w2r(256)] rows, N=3328
__global__ __launch_bounds__(256) void qkv_lines_gemm128(
    const bhalf* __restrict__ x, const bhalf* __restrict__ wcat, const float* __restrict__ bqkv,
    bhalf* __restrict__ qo, bhalf* __restrict__ ko, bhalf* __restrict__ vt,
    float* __restrict__ proj)
{
    __shared__ bhalf As[128 * 64];
    __shared__ bhalf Bs[128 * 64];
    f32x4 acc[4][4] = {};
    gemm128_mainloop(x + (size_t)blockIdx.x * 128 * D_DIM,
                     wcat + (size_t)blockIdx.y * 128 * D_DIM, D_DIM, As, Bs, acc);
    const int wave = threadIdx.x >> 6, lane = threadIdx.x & 63;
    const int ln = lane & 15, lg = lane >> 4;
    const int wr = (wave >> 1) * 64, wc = (wave & 1) * 64;
    const int trip = (blockIdx.y * 128) >> 10;   // uniform per block (128 | 1024)

    if (trip == 2) {
        // v^T: pack 4 consecutive-t values -> one 8B store per (mt,nt)
#pragma unroll
        for (int nt = 0; nt < 4; ++nt) {
            int n = blockIdx.y * 128 + wc + nt * 16 + ln;
            float bias = bqkv[n];
            int h = (n >> 6) & 15, d = n & 63;
#pragma unroll
            for (int mt = 0; mt < 4; ++mt) {
                int tok0 = blockIdx.x * 128 + wr + mt * 16 + lg * 4;
                int b = tok0 >> 11, t0 = tok0 & (T_DIM - 1);
                bh4 pk;
#pragma unroll
                for (int r = 0; r < 4; ++r)
                    pk.v[r] = __float2bfloat16(acc[mt][nt][r] + bias);
                *(uint2*)&vt[(((size_t)(b * H_DIM + h)) * DH + d) * T_DIM + t0] =
                    __builtin_bit_cast(uint2, pk);
            }
        }
    } else {
#pragma unroll
        for (int nt = 0; nt < 4; ++nt) {
            int n = blockIdx.y * 128 + wc + nt * 16 + ln;
            int h = (n >> 6) & 15, d = n & 63;
            float bias = (trip < 3) ? bqkv[n] : 0.f;
#pragma unroll
            for (int mt = 0; mt < 4; ++mt)
#pragma unroll
                for (int r = 0; r < 4; ++r) {
                    int tok = blockIdx.x * 128 + wr + mt * 16 + lg * 4 + r;
                    int b = tok >> 11, t = tok & (T_DIM - 1);
                    float y = acc[mt][nt][r] + bias;
                    if (trip == 0) {
                        qo[(((size_t)(b * H_DIM + h)) * T_DIM + t) * DH + d] = __float2bfloat16(y * 0.125f);
                    } else if (trip == 1) {
                        ko[(((size_t)(b * H_DIM + h)) * T_DIM + t) * DH + d] = __float2bfloat16(y);
                    } else {
                        proj[(size_t)tok * 256 + (n - 3072)] = y;
                    }
                }
        }
    }
}

// 64x64 bf16 GEMM with global_load_lds staging (out projection; 1024 blocks)
__global__ __launch_bounds__(256) void out_gemm64(
    const bhalf* __restrict__ a, const bhalf* __restrict__ w, const float* __restrict__ bo,
    float* __restrict__ out)
{
    __shared__ bhalf As[64 * 64];
    __shared__ bhalf Bs[64 * 64];
    const int tid = threadIdx.x;
    const int wave = tid >> 6, lane = tid & 63;
    const int ln = lane & 15, lg = lane >> 4;
    const int lrow = lane >> 3;
    const int lcol = (lane & 7) * 8;
    const bhalf* A = a + (size_t)blockIdx.x * 64 * D_DIM;
    const bhalf* B = w + (size_t)blockIdx.y * 64 * D_DIM;
    f32x4 acc[4] = {};

    for (int kt = 0; kt < D_DIM; kt += 64) {
        __syncthreads();
#pragma unroll
        for (int i = 0; i < 2; ++i) {
            int idx = __builtin_amdgcn_readfirstlane(wave * 2 + i);
            GLD16(A + (size_t)(idx * 8 + lrow) * D_DIM + kt + lcol, As + idx * 512);
            GLD16(B + (size_t)(idx * 8 + lrow) * D_DIM + kt + lcol, Bs + idx * 512);
        }
        __syncthreads();
#pragma unroll
        for (int ks = 0; ks < 2; ++ks) {
            bf16x8 af = load_bf16x8(As + (wave * 16 + ln) * 64 + ks * 32 + lg * 8);
#pragma unroll
            for (int nt = 0; nt < 4; ++nt) {
                bf16x8 bfr = load_bf16x8(Bs + (nt * 16 + ln) * 64 + ks * 32 + lg * 8);
                acc[nt] = __builtin_amdgcn_mfma_f32_16x16x32_bf16(af, bfr, acc[nt], 0, 0, 0);
            }
        }
    }
#pragma unroll
    for (int nt = 0; nt < 4; ++nt) {
        int n = blockIdx.y * 64 + nt * 16 + ln;
        float bias = bo[n];
#pragma unroll
        for (int r = 0; r < 4; ++r) {
            int tok = blockIdx.x * 64 + wave * 16 + lg * 4 + r;
            out[(size_t)tok * D_DIM + n] = acc[nt][r] + bias;
        }
    }
}

__global__ __launch_bounds__(256) void build_lines(
    const float* __restrict__ proj, const float* __restrict__ bias_scale,
    const float* __restrict__ decay_logits,
    bhalf* __restrict__ read8, bhalf* __restrict__ jw8)
{
    int id = blockIdx.x * 256 + threadIdx.x;
    int tok = id >> 4, h = id & 15;
    int b = tok >> 11, t = tok & (T_DIM - 1);
    const float* pr = proj + (size_t)tok * 256;

    float p1[4], p2[4], r1[4], r2[4];
#pragma unroll
    for (int i = 0; i < 4; ++i) {
        p1[i] = (t > 0) ? pr[-256 + h * 4 + i] : 0.f;
        p2[i] = pr[64 + h * 4 + i];
        r1[i] = pr[128 + h * 4 + i];
        r2[i] = pr[192 + h * 4 + i];
    }
    float Lw[6], Lr[6];
    {
        Lw[0] = p1[0] * p2[1] - p1[1] * p2[0];
        Lw[1] = p1[0] * p2[2] - p1[2] * p2[0];
        Lw[2] = p1[0] * p2[3] - p1[3] * p2[0];
        Lw[3] = p1[1] * p2[2] - p1[2] * p2[1];
        Lw[4] = p1[1] * p2[3] - p1[3] * p2[1];
        Lw[5] = p1[2] * p2[3] - p1[3] * p2[2];
        float n2 = 0.f;
#pragma unroll
        for (int j = 0; j < 6; ++j) n2 += Lw[j] * Lw[j];
        float inv = 1.f / fmaxf(sqrtf(n2), 1e-12f);
#pragma unroll
        for (int j = 0; j < 6; ++j) Lw[j] *= inv;
    }
    {
        Lr[0] = r1[0] * r2[1] - r1[1] * r2[0];
        Lr[1] = r1[0] * r2[2] - r1[2] * r2[0];
        Lr[2] = r1[0] * r2[3] - r1[3] * r2[0];
        Lr[3] = r1[1] * r2[2] - r1[2] * r2[1];
        Lr[4] = r1[1] * r2[3] - r1[3] * r2[1];
        Lr[5] = r1[2] * r2[3] - r1[3] * r2[2];
        float n2 = 0.f;
#pragma unroll
        for (int j = 0; j < 6; ++j) n2 += Lr[j] * Lr[j];
        float inv = 1.f / fmaxf(sqrtf(n2), 1e-12f);
#pragma unroll
        for (int j = 0; j < 6; ++j) Lr[j] *= inv;
    }
    float decay = 1.f / (1.f + __expf(-decay_logits[h]));
    float l2d = log2f(decay);
    float bs = bias_scale[h] * exp2f(-(float)t * l2d);
    size_t base = (((size_t)(b * H_DIM + h)) * T_DIM + t) * 8;
    read8[base + 0] = __float2bfloat16(Lr[0]);
    read8[base + 1] = __float2bfloat16(Lr[1]);
    read8[base + 2] = __float2bfloat16(Lr[2]);
    read8[base + 3] = __float2bfloat16(Lr[3]);
    read8[base + 4] = __float2bfloat16(Lr[4]);
    read8[base + 5] = __float2bfloat16(Lr[5]);
    read8[base + 6] = __float2bfloat16(0.f);
    read8[base + 7] = __float2bfloat16(0.f);
    jw8[base + 0] = __float2bfloat16(Lw[5] * bs);
    jw8[base + 1] = __float2bfloat16(-Lw[4] * bs);
    jw8[base + 2] = __float2bfloat16(Lw[3] * bs);
    jw8[base + 3] = __float2bfloat16(Lw[2] * bs);
    jw8[base + 4] = __float2bfloat16(-Lw[1] * bs);
    jw8[base + 5] = __float2bfloat16(Lw[0] * bs);
    jw8[base + 6] = __float2bfloat16(0.f);
    jw8[base + 7] = __float2bfloat16(0.f);
}

// softmax tile step: scores -> P (packed bf16x2 stores), k-cols = kb+2*ln (+1)
template<bool DIAG>
__device__ __forceinline__ void tile_step(
    const f32x4& z0, const f32x4& z1, const f32x4& i0, const f32x4& i1,
    int rq, int kb, const float* aq, int lg, int ln, bhalf* pl, float* lp)
{
    const float LOG2E = 1.44269504f;
#pragma unroll
    for (int r = 0; r < 4; ++r) {
        float p0, p1;
        if (DIAG) {
            int diff0 = rq + lg * 4 + r - (kb + 2 * ln);
            float s0 = z0[r] + ((diff0 > 0) ? i0[r] * aq[r] : 0.f);
            p0 = (diff0 < 0) ? 0.f : exp2f(s0 * LOG2E);
            int diff1 = diff0 - 1;
            float s1 = z1[r] + ((diff1 > 0) ? i1[r] * aq[r] : 0.f);
            p1 = (diff1 < 0) ? 0.f : exp2f(s1 * LOG2E);
        } else {
            p0 = exp2f(fmaf(i0[r], aq[r], z0[r]) * LOG2E);
            p1 = exp2f(fmaf(i1[r], aq[r], z1[r]) * LOG2E);
        }
        bf16x2 h2;
        h2.x = (__bf16)p0;
        h2.y = (__bf16)p1;
        *(unsigned int*)&pl[(lg * 4 + r) * 40 + 2 * ln] = __builtin_bit_cast(unsigned int, h2);
        lp[r] += p0 + p1;
    }
}

// Attention, antithetic-paired, paired-k, fast/diag paths.
// 1-D grid (2048) with XCD-partitioned decode: xcd = bx&7 owns 4 (b,h) pairs,
// so each head's 512KB K/V stays in ONE XCD's 4MB L2 (latency: HBM->L2 hits).
__global__ __launch_bounds__(256) void attn_kernel(
    const bhalf* __restrict__ q, const bhalf* __restrict__ k, const bhalf* __restrict__ vt,
    const bhalf* __restrict__ read8, const bhalf* __restrict__ jw8,
    const float* __restrict__ decay_logits, bhalf* __restrict__ attn_out)
{
    __shared__ float sm[4352];   // 17408 B
    const int wave = threadIdx.x >> 6, lane = threadIdx.x & 63;
    const int ln = lane & 15, lg = lane >> 4;
    const int bx = blockIdx.x;             // 0..2047
    const int xcd = bx & 7;
    const int slot = bx >> 3;              // 0..255
    const int hbid = xcd * 4 + (slot >> 6);  // 0..31
    const int h = hbid & 15, b = hbid >> 4;
    const int qa = slot & 63;
    const int qb = 127 - qa;
    const int rqa = qa * 16, rqb = qb * 16;
    const size_t hb = (size_t)(b * H_DIM + h);
    const bhalf* qh = q + hb * T_DIM * DH;
    const bhalf* kh = k + hb * T_DIM * DH;
    const bhalf* vh = vt + hb * DH * T_DIM;
    const bhalf* r8 = read8 + hb * T_DIM * 8;
    const bhalf* j8 = jw8 + hb * T_DIM * 8;

    bhalf* plA = (bhalf*)sm + wave * 640;
    bhalf* plB = (bhalf*)sm + 2560 + wave * 640;

    bf16x8 zf = zero_bf16x8();
    bf16x8 qA0 = load_bf16x8(qh + (rqa + ln) * DH + lg * 8);
    bf16x8 qA1 = load_bf16x8(qh + (rqa + ln) * DH + 32 + lg * 8);
    bf16x8 qB0 = load_bf16x8(qh + (rqb + ln) * DH + lg * 8);
    bf16x8 qB1 = load_bf16x8(qh + (rqb + ln) * DH + 32 + lg * 8);
    bf16x8 rfA = (lane < 16) ? load_bf16x8(r8 + (size_t)(rqa + ln) * 8) : zf;
    bf16x8 rfB = (lane < 16) ? load_bf16x8(r8 + (size_t)(rqb + ln) * 8) : zf;

    float decay = 1.f / (1.f + __expf(-decay_logits[h]));
    float l2d = log2f(decay);
    float aqA[4], aqB[4];
#pragma unroll
    for (int r = 0; r < 4; ++r) {
        aqA[r] = exp2f((float)(rqa + lg * 4 + r) * l2d);
        aqB[r] = exp2f((float)(rqb + lg * 4 + r) * l2d);
    }

    f32x4 oA[4] = {}, oB[4] = {};
    float lpA[4] = {0.f, 0.f, 0.f, 0.f}, lpB[4] = {0.f, 0.f, 0.f, 0.f};

    const int nca = qa / 2 + 1, ncb = qb / 2 + 1;
    for (int c = wave; c < ncb; c += 4) {
        const int kb = c * 32;
        bf16x8 k00 = load_bf16x8(kh + (kb + 2 * ln) * DH + lg * 8);
        bf16x8 k01 = load_bf16x8(kh + (kb + 2 * ln) * DH + 32 + lg * 8);
        bf16x8 k10 = load_bf16x8(kh + (kb + 2 * ln + 1) * DH + lg * 8);
        bf16x8 k11 = load_bf16x8(kh + (kb + 2 * ln + 1) * DH + 32 + lg * 8);
        bf16x8 j0 = (lane < 16) ? load_bf16x8(j8 + (size_t)(kb + 2 * ln) * 8) : zf;
        bf16x8 j1 = (lane < 16) ? load_bf16x8(j8 + (size_t)(kb + 2 * ln + 1) * 8) : zf;
        bf16x8 vf0 = load_bf16x8(vh + (size_t)(ln) * T_DIM + kb + lg * 8);
        bf16x8 vf1 = load_bf16x8(vh + (size_t)(16 + ln) * T_DIM + kb + lg * 8);
        bf16x8 vf2 = load_bf16x8(vh + (size_t)(32 + ln) * T_DIM + kb + lg * 8);
        bf16x8 vf3 = load_bf16x8(vh + (size_t)(48 + ln) * T_DIM + kb + lg * 8);
        const bool doA = (c < nca);

        {
            f32x4 z0 = {}, z1 = {}, i0 = {}, i1 = {};
            z0 = __builtin_amdgcn_mfma_f32_16x16x32_bf16(qB0, k00, z0, 0, 0, 0);
            z0 = __builtin_amdgcn_mfma_f32_16x16x32_bf16(qB1, k01, z0, 0, 0, 0);
            i0 = __builtin_amdgcn_mfma_f32_16x16x32_bf16(rfB, j0, i0, 0, 0, 0);
            z1 = __builtin_amdgcn_mfma_f32_16x16x32_bf16(qB0, k10, z1, 0, 0, 0);
            z1 = __builtin_amdgcn_mfma_f32_16x16x32_bf16(qB1, k11, z1, 0, 0, 0);
            i1 = __builtin_amdgcn_mfma_f32_16x16x32_bf16(rfB, j1, i1, 0, 0, 0);
            if (c == ncb - 1) tile_step<true >(z0, z1, i0, i1, rqb, kb, aqB, lg, ln, plB, lpB);
            else              tile_step<false>(z0, z1, i0, i1, rqb, kb, aqB, lg, ln, plB, lpB);
        }
        if (doA) {
            f32x4 z0 = {}, z1 = {}, i0 = {}, i1 = {};
            z0 = __builtin_amdgcn_mfma_f32_16x16x32_bf16(qA0, k00, z0, 0, 0, 0);
            z0 = __builtin_amdgcn_mfma_f32_16x16x32_bf16(qA1, k01, z0, 0, 0, 0);
            i0 = __builtin_amdgcn_mfma_f32_16x16x32_bf16(rfA, j0, i0, 0, 0, 0);
            z1 = __builtin_amdgcn_mfma_f32_16x16x32_bf16(qA0, k10, z1, 0, 0, 0);
            z1 = __builtin_amdgcn_mfma_f32_16x16x32_bf16(qA1, k11, z1, 0, 0, 0);
            i1 = __builtin_amdgcn_mfma_f32_16x16x32_bf16(rfA, j1, i1, 0, 0, 0);
            if (c == nca - 1) tile_step<true >(z0, z1, i0, i1, rqa, kb, aqA, lg, ln, plA, lpA);
            else              tile_step<false>(z0, z1, i0, i1, rqa, kb, aqA, lg, ln, plA, lpA);
        }
        __asm__ volatile("s_waitcnt lgkmcnt(0)" ::: "memory");
        {
            bf16x8 pf = load_bf16x8(plB + ln * 40 + lg * 8);
            oB[0] = __builtin_amdgcn_mfma_f32_16x16x32_bf16(pf, vf0, oB[0], 0, 0, 0);
            oB[1] = __builtin_amdgcn_mfma_f32_16x16x32_bf16(pf, vf1, oB[1], 0, 0, 0);
            oB[2] = __builtin_amdgcn_mfma_f32_16x16x32_bf16(pf, vf2, oB[2], 0, 0, 0);
            oB[3] = __builtin_amdgcn_mfma_f32_16x16x32_bf16(pf, vf3, oB[3], 0, 0, 0);
        }
        if (doA) {
            bf16x8 pf = load_bf16x8(plA + ln * 40 + lg * 8);
            oA[0] = __builtin_amdgcn_mfma_f32_16x16x32_bf16(pf, vf0, oA[0], 0, 0, 0);
            oA[1] = __builtin_amdgcn_mfma_f32_16x16x32_bf16(pf, vf1, oA[1], 0, 0, 0);
            oA[2] = __builtin_amdgcn_mfma_f32_16x16x32_bf16(pf, vf2, oA[2], 0, 0, 0);
            oA[3] = __builtin_amdgcn_mfma_f32_16x16x32_bf16(pf, vf3, oA[3], 0, 0, 0);
        }
    }

#pragma unroll
    for (int r = 0; r < 4; ++r) {
#pragma unroll
        for (int off = 1; off < 16; off <<= 1) {
            lpA[r] += __shfl_xor(lpA[r], off, 16);
            lpB[r] += __shfl_xor(lpB[r], off, 16);
        }
    }

    const int row = threadIdx.x >> 4;
    const int c4 = (threadIdx.x & 15) * 4;

    __syncthreads();
#pragma unroll
    for (int r = 0; r < 4; ++r) {
        if (ln == 0) sm[wave * 1088 + (lg * 4 + r) * 68 + 64] = lpA[r];
#pragma unroll
        for (int nt = 0; nt < 4; ++nt)
            sm[wave * 1088 + (lg * 4 + r) * 68 + nt * 16 + ln] = oA[nt][r];
    }
    __syncthreads();
    {
        float l = 0.f;
#pragma unroll
        for (int w = 0; w < 4; ++w) l += sm[w * 1088 + row * 68 + 64];
        float4 acc = {0.f, 0.f, 0.f, 0.f};
#pragma unroll
        for (int w = 0; w < 4; ++w) {
            float4 t = *(const float4*)&sm[w * 1088 + row * 68 + c4];
            acc.x += t.x; acc.y += t.y; acc.z += t.z; acc.w += t.w;
        }
        float invl = 1.f / l;
        bh4 pk;
        pk.v[0] = __float2bfloat16(acc.x * invl);
        pk.v[1] = __float2bfloat16(acc.y * invl);
        pk.v[2] = __float2bfloat16(acc.z * invl);
        pk.v[3] = __float2bfloat16(acc.w * invl);
        size_t tok = (size_t)b * T_DIM + rqa + row;
        *(uint2*)&attn_out[tok * D_DIM + h * DH + c4] = __builtin_bit_cast(uint2, pk);
    }

    __syncthreads();
#pragma unroll
    for (int r = 0; r < 4; ++r) {
        if (ln == 0) sm[wave * 1088 + (lg * 4 + r) * 68 + 64] = lpB[r];
#pragma unroll
        for (int nt = 0; nt < 4; ++nt)
            sm[wave * 1088 + (lg * 4 + r) * 68 + nt * 16 + ln] = oB[nt][r];
    }
    __syncthreads();
    {
        float l = 0.f;
#pragma unroll
        for (int w = 0; w < 4; ++w) l += sm[w * 1088 + row * 68 + 64];
        float4 acc = {0.f, 0.f, 0.f, 0.f};
#pragma unroll
        for (int w = 0; w < 4; ++w) {
            float4 t = *(const float4*)&sm[w * 1088 + row * 68 + c4];
            acc.x += t.x; acc.y += t.y; acc.z += t.z; acc.w += t.w;
        }
        float invl = 1.f / l;
        bh4 pk;
        pk.v[0] = __float2bfloat16(acc.x * invl);
        pk.v[1] = __float2bfloat16(acc.y * invl);
        pk.v[2] = __float2bfloat16(acc.z * invl);
        pk.v[3] = __float2bfloat16(acc.w * invl);
        size_t tok = (size_t)b * T_DIM + rqb + row;
        *(uint2*)&attn_out[tok * D_DIM + h * DH + c4] = __builtin_bit_cast(uint2, pk);
    }
}

extern "C" void kernel_launch(void* const* d_in, const int* in_sizes, int n_in,
                              void* d_out, int out_size, void* d_ws, size_t ws_size,
                              hipStream_t stream)
{
    const float* x    = (const float*)d_in[0];
    const float* wqkv = (const float*)d_in[1];
    const float* bqkv = (const float*)d_in[2];
    const float* w1w  = (const float*)d_in[3];
    const float* w2w  = (const float*)d_in[4];
    const float* w1r  = (const float*)d_in[5];
    const float* w2r  = (const float*)d_in[6];
    const float* wout = (const float*)d_in[7];
    const float* bout = (const float*)d_in[8];
    const float* dlog = (const float*)d_in[9];
    const float* bsc  = (const float*)d_in[10];
    float* out = (float*)d_out;

    char* ws = (char*)d_ws;
    bhalf* qb    = (bhalf*)(ws);                 // [B,H,T,64] bf16   8388608 B
    bhalf* kbuf  = (bhalf*)(ws + 8388608);       // [B,H,T,64] bf16   8388608 B
    bhalf* vtb   = (bhalf*)(ws + 16777216);      // [B,H,64,T] bf16   8388608 B
    bhalf* r8    = (bhalf*)(ws + 25165824);      // [B,H,T,8]  bf16   1048576 B
    bhalf* j8    = (bhalf*)(ws + 26214400);      // [B,H,T,8]  bf16   1048576 B
    float* proj  = (float*)(ws + 27262976);      // [B*T,256]  f32    4194304 B
    bhalf* ao    = (bhalf*)(ws + 31457280);      // [B*T,1024] bf16   8388608 B
    bhalf* woutbf = (bhalf*)(ws + 39845888);     // [1024,1024] bf16  2097152 B

    bhalf* xbf  = (bhalf*)d_out;                      //  8388608 B
    bhalf* wcat = (bhalf*)((char*)d_out + 8388608);   //  6815744 B (3328x1024)

    cvt_all<<<4224, 256, 0, stream>>>(x, wqkv, w1w, w2w, w1r, w2r, wout, xbf, wcat, woutbf);
    qkv_lines_gemm128<<<dim3(32, 26), 256, 0, stream>>>(xbf, wcat, bqkv, qb, kbuf, vtb, proj);
    build_lines<<<256, 256, 0, stream>>>(proj, bsc, dlog, r8, j8);
    attn_kernel<<<2048, 256, 0, stream>>>(qb, kbuf, vtb, r8, j8, dlog, ao);
    out_gemm64<<<dim3(64, 16), 256, 0, stream>>>(ao, woutbf, bout, out);
}